// Round 12
// baseline (331.231 us; speedup 1.0000x reference)
//
#include <hip/hip_runtime.h>
#include <hip/hip_bf16.h>
#include <hip/hip_fp16.h>

// R18: gemm_mfma_8ph K-step interior UNPINNED.
//   R17 confirmed VALU theory (32->21) but dur barely moved -> critical path
//   is the 4x per-K-step lgkmcnt(0)+sched_barrier(0) pins, each exposing
//   ~120cyc ds_read latency the compiler is forbidden to hide (m141: pin-
//   heavy = 510TF; m97: unpinned compiler scheduling = 874TF on the same
//   2-barrier skeleton; we sit at ~410TF effective).
//   Change: plain C++ frag loads (2 quad groups), NO intra-step asm pins;
//   compiler emits fine-grained counted lgkmcnt. ONE lgkmcnt(0)+fence per
//   K-step before barrier#2 (correctness: reads of buf[p] must complete
//   before stage(p,t+2) overwrites it). vmcnt/barrier/stage macro-structure,
//   swizzle, XCD remap, full unroll all unchanged. Bit-identical k-order.
// Everything else unchanged from R17.

using f16 = _Float16;
typedef _Float16 f16x8 __attribute__((ext_vector_type(8)));
typedef _Float16 f16x2 __attribute__((ext_vector_type(2)));
typedef float    f32x4 __attribute__((ext_vector_type(4)));

__device__ inline void storeC(float* p, float v) { *p = v; }
__device__ inline void storeC(f16* p, float v)   { *p = (f16)v; }

__device__ inline void async_cp16(const f16* g, f16* l) {
    __builtin_amdgcn_global_load_lds(
        (const __attribute__((address_space(1))) unsigned int*)g,
        (__attribute__((address_space(3))) unsigned int*)l,
        16, 0, 0);
}

// ---------------------------------------------------------------------------
// prep_all (unchanged)
// ---------------------------------------------------------------------------
__global__ __launch_bounds__(256) void prep_all(
    const float* __restrict__ x, const float* __restrict__ Wqkv,
    const float* __restrict__ Wf, const float* __restrict__ Wo,
    const float* __restrict__ bo, const float* __restrict__ bfv,
    f16* __restrict__ xh, f16* __restrict__ wqkvh, f16* __restrict__ wfh,
    f16* __restrict__ WoT, float* __restrict__ bp)
{
    __shared__ float t[32][33];
    const int bid = blockIdx.x;
    const int tid = threadIdx.x;

    if (bid < 5632) {
        const float* in; f16* outp; int base;
        if (bid < 4096)      { in = x;    outp = xh;    base = bid; }
        else if (bid < 5248) { in = Wqkv; outp = wqkvh; base = bid - 4096; }
        else                 { in = Wf;   outp = wfh;   base = bid - 5248; }
        int i = (base * 256 + tid) * 8;
        float4 a = *(const float4*)(in + i);
        float4 b = *(const float4*)(in + i + 4);
        f16x8 h = { (f16)a.x, (f16)a.y, (f16)a.z, (f16)a.w,
                    (f16)b.x, (f16)b.y, (f16)b.z, (f16)b.w };
        *(f16x8*)(outp + i) = h;
    } else if (bid < 6400) {
        const int idx = bid - 5632;
        const int z  = idx >> 8;
        const int bx = (idx & 15) * 32;
        const int by = ((idx >> 4) & 15) * 32;
        const int tx = tid & 31;
        const int ty = tid >> 5;
#pragma unroll
        for (int r = ty; r < 32; r += 8)
            t[r][tx] = Wo[(size_t)z * 262144 + (by + r) * 512 + bx + tx];
        __syncthreads();
#pragma unroll
        for (int r = ty; r < 32; r += 8)
            WoT[(size_t)z * 262144 + (bx + r) * 512 + by + tx] = (f16)t[tx][r];
    } else {
        const int o = (bid - 6400) * 4 + (tid >> 6);
        const int lane = tid & 63;
        float s = 0.f;
        for (int j = lane; j < 1536; j += 64) s += Wf[o * 1536 + j] * bo[j];
#pragma unroll
        for (int msk = 1; msk < 64; msk <<= 1) s += __shfl_xor(s, msk, 64);
        if (lane == 0) bp[o] = s + bfv[o];
    }
}

// ---------------------------------------------------------------------------
// small 128x128 2-phase GEMM (Wfo product only)
// ---------------------------------------------------------------------------
template <typename TC>
__global__ __launch_bounds__(256) void gemm_mfma_nt(
    const f16* __restrict__ A, int lda, long azs,
    const f16* __restrict__ B, int ldb, long bzs,
    const float* __restrict__ bias,
    TC* __restrict__ C, int ldc, long czs,
    int K)
{
    __shared__ __align__(16) f16 As[2][128 * 32];
    __shared__ __align__(16) f16 Bs[2][128 * 32];

    const int tid  = threadIdx.x;
    const int lane = tid & 63;
    const int wave = tid >> 6;
    const int wm = (wave >> 1) * 64;
    const int wn = (wave & 1) * 64;
    const int bm = blockIdx.y * 128;
    const int bn = blockIdx.x * 128;
    const int z  = blockIdx.z;

    const int srow = tid >> 2;
    const int scol = (tid & 3) * 8;
    const int soff = srow * 32 + scol;

    const f16* Ag = A + (size_t)z * azs + (size_t)(bm + srow) * lda + scol;
    const f16* Bg = B + (size_t)z * bzs + (size_t)(bn + srow) * ldb + scol;

    f32x4 acc[4][4];
#pragma unroll
    for (int i = 0; i < 4; ++i)
#pragma unroll
        for (int j = 0; j < 4; ++j)
            acc[i][j] = (f32x4){0.f, 0.f, 0.f, 0.f};

    const int fr = lane & 15;
    const int fk = (lane >> 4) * 8;

    async_cp16(Ag, &As[0][soff]);
    async_cp16(Ag + (size_t)64 * lda, &As[0][soff + 64 * 32]);
    async_cp16(Bg, &Bs[0][soff]);
    async_cp16(Bg + (size_t)64 * ldb, &Bs[0][soff + 64 * 32]);

    const int nt = K >> 5;
    for (int t = 0; t < nt; ++t) {
        __syncthreads();
        const int p = t & 1;
        if (t + 1 < nt) {
            const int k1 = (t + 1) * 32;
            async_cp16(Ag + k1, &As[p ^ 1][soff]);
            async_cp16(Ag + k1 + (size_t)64 * lda, &As[p ^ 1][soff + 64 * 32]);
            async_cp16(Bg + k1, &Bs[p ^ 1][soff]);
            async_cp16(Bg + k1 + (size_t)64 * ldb, &Bs[p ^ 1][soff + 64 * 32]);
        }

        f16x8 af[4], bfr[4];
#pragma unroll
        for (int i = 0; i < 4; ++i)
            af[i] = *(const f16x8*)&As[p][(wm + i * 16 + fr) * 32 + fk];
#pragma unroll
        for (int j = 0; j < 4; ++j)
            bfr[j] = *(const f16x8*)&Bs[p][(wn + j * 16 + fr) * 32 + fk];
#pragma unroll
        for (int i = 0; i < 4; ++i)
#pragma unroll
            for (int j = 0; j < 4; ++j)
                acc[i][j] = __builtin_amdgcn_mfma_f32_16x16x32_f16(
                    af[i], bfr[j], acc[i][j], 0, 0, 0);
    }

    const int cn  = lane & 15;
    const int cr4 = (lane >> 4) * 4;
#pragma unroll
    for (int i = 0; i < 4; ++i) {
#pragma unroll
        for (int j = 0; j < 4; ++j) {
            const int col = bn + wn + j * 16 + cn;
            const float bv = bias ? bias[col] : 0.f;
#pragma unroll
            for (int r = 0; r < 4; ++r) {
                const int row = bm + wm + i * 16 + cr4 + r;
                storeC(&C[(size_t)z * czs + (size_t)row * ldc + col],
                       acc[i][j][r] + bv);
            }
        }
    }
}

// ---------------------------------------------------------------------------
// 8ph-skeleton GEMM, BM=128, 2 blocks/CU, XCD swizzle, compile-time NT,
// UNPINNED K-step interior (compiler-scheduled ds_read/MFMA interleave).
// BN = NR*64. grid = (GX, 128, z); GX = 8 (NR=3) or 4 (NR=2).
// ---------------------------------------------------------------------------
template <int NR, int NT, typename TC>
__global__ __launch_bounds__(512, 4) void gemm_mfma_8ph(
    const f16* __restrict__ A, int lda,
    const f16* __restrict__ B, int ldb, long bzs,
    const float* __restrict__ bias, long bizs,
    TC* __restrict__ C, int ldc, long czs)
{
    __shared__ __align__(16) f16 As[2][128 * 64];
    __shared__ __align__(16) f16 Bs[2][NR * 64 * 64];

    const int z = blockIdx.z;
    B += (size_t)z * bzs;
    C += (size_t)z * czs;
    const float* biasz = bias ? bias + (size_t)z * bizs : nullptr;

    // XCD-chunked bijective swizzle; nwg = GX*128, nwg%8==0.
    constexpr int GX   = (NR == 3) ? 8 : 4;
    constexpr int LGX  = (NR == 3) ? 3 : 2;
    const int raw = blockIdx.y * GX + blockIdx.x;
    const int lid = (raw & 7) * (GX * 16) + (raw >> 3);
    const int bxs = lid & (GX - 1);
    const int bys = lid >> LGX;

    const int tid  = threadIdx.x;
    const int lane = tid & 63;
    const int wave = tid >> 6;
    const int wr = wave >> 2;            // 0..1 (M wave, 64 rows each)
    const int wc = wave & 3;             // 0..3 (N wave, NR*16 cols each)
    const int bm = bys * 128;
    const int bn = bxs * (NR * 64);
    const int fr  = lane & 15;
    const int grp = lane >> 4;

    const int c0 = ((0 + grp) ^ (fr & 7)) * 8;
    const int c1 = ((4 + grp) ^ (fr & 7)) * 8;

    const int srow = tid >> 3;
    const int scol = ((tid & 7) ^ (srow & 7)) * 8;
    const f16* Ag = A + (size_t)(bm + srow) * lda + scol;
    const f16* Bg = B + (size_t)(bn + srow) * ldb + scol;

    f32x4 acc[4][NR];
#pragma unroll
    for (int m = 0; m < 4; ++m)
#pragma unroll
        for (int n = 0; n < NR; ++n)
            acc[m][n] = (f32x4){0.f, 0.f, 0.f, 0.f};

    const int arow = wr * 64 + fr;
    const int brow = wc * (NR * 16) + fr;

    auto stage = [&](int p, int kt) {
        const f16* a_ = Ag + (size_t)kt * 64;
        const f16* b_ = Bg + (size_t)kt * 64;
        f16* al = &As[p][tid * 8];
        f16* bl = &Bs[p][tid * 8];
#pragma unroll
        for (int i = 0; i < 2; ++i)
            async_cp16(a_ + (size_t)(i * 64) * lda, al + i * 4096);
#pragma unroll
        for (int i = 0; i < NR; ++i)
            async_cp16(b_ + (size_t)(i * 64) * ldb, bl + i * 4096);
    };

    stage(0, 0);
    stage(1, 1);

#pragma unroll
    for (int t = 0; t < NT; ++t) {
        const int p = t & 1;            // compile-time after unroll
        if (t + 1 < NT) {
            // one tile (2+NR loads) in flight across the compute
            if constexpr (NR == 3)
                asm volatile("s_waitcnt vmcnt(5)" ::: "memory");
            else
                asm volatile("s_waitcnt vmcnt(4)" ::: "memory");
        } else {
            asm volatile("s_waitcnt vmcnt(0)" ::: "memory");
        }
        __builtin_amdgcn_s_barrier();

        const f16* asb = As[p];
        const f16* bsb = Bs[p];

        // UNPINNED: plain loads, compiler emits fine-grained counted lgkmcnt
        // and interleaves ds_read with MFMA freely.
        f16x8 bfrag[NR][2];
#pragma unroll
        for (int n = 0; n < NR; ++n) {
            const int ro = (brow + n * 16) * 64;
            bfrag[n][0] = *(const f16x8*)&bsb[ro + c0];
            bfrag[n][1] = *(const f16x8*)&bsb[ro + c1];
        }

        f16x8 aP[2][2];
#pragma unroll
        for (int m2 = 0; m2 < 2; ++m2) {
            const int ro = (arow + m2 * 16) * 64;
            aP[m2][0] = *(const f16x8*)&asb[ro + c0];
            aP[m2][1] = *(const f16x8*)&asb[ro + c1];
        }
        __builtin_amdgcn_s_setprio(1);
#pragma unroll
        for (int m2 = 0; m2 < 2; ++m2)
#pragma unroll
            for (int n = 0; n < NR; ++n) {
                f32x4 zz = __builtin_amdgcn_mfma_f32_16x16x32_f16(
                    aP[m2][0], bfrag[n][0], acc[m2][n], 0, 0, 0);
                acc[m2][n] = __builtin_amdgcn_mfma_f32_16x16x32_f16(
                    aP[m2][1], bfrag[n][1], zz, 0, 0, 0);
            }
        __builtin_amdgcn_s_setprio(0);

        f16x8 aQ[2][2];
#pragma unroll
        for (int m2 = 0; m2 < 2; ++m2) {
            const int ro = (arow + (2 + m2) * 16) * 64;
            aQ[m2][0] = *(const f16x8*)&asb[ro + c0];
            aQ[m2][1] = *(const f16x8*)&asb[ro + c1];
        }
        __builtin_amdgcn_s_setprio(1);
#pragma unroll
        for (int m2 = 0; m2 < 2; ++m2)
#pragma unroll
            for (int n = 0; n < NR; ++n) {
                f32x4 zz = __builtin_amdgcn_mfma_f32_16x16x32_f16(
                    aQ[m2][0], bfrag[n][0], acc[2 + m2][n], 0, 0, 0);
                acc[2 + m2][n] = __builtin_amdgcn_mfma_f32_16x16x32_f16(
                    aQ[m2][1], bfrag[n][1], zz, 0, 0, 0);
            }
        __builtin_amdgcn_s_setprio(0);

        // correctness fence: all reads of buf[p] complete before the
        // post-barrier stage(p, t+2) overwrites it.
        asm volatile("s_waitcnt lgkmcnt(0)" ::: "memory");
        __builtin_amdgcn_s_barrier();
        if (t + 2 < NT) stage(p, t + 2);
    }

    const int cn  = lane & 15;
    const int cr4 = (lane >> 4) * 4;
#pragma unroll
    for (int m = 0; m < 4; ++m)
#pragma unroll
        for (int n = 0; n < NR; ++n) {
            const int col = bn + wc * (NR * 16) + n * 16 + cn;
            const float bv = biasz ? biasz[col] : 0.f;
#pragma unroll
            for (int r = 0; r < 4; ++r) {
                const int row = bm + wr * 64 + m * 16 + cr4 + r;
                storeC(&C[(size_t)row * ldc + col], acc[m][n][r] + bv);
            }
        }
}

// ---------------------------------------------------------------------------
// Windowed attention body v2 (unchanged)
// ---------------------------------------------------------------------------
__device__ __forceinline__ void win_attn_body(
    const f16* __restrict__ qkv, f16* __restrict__ out, f16* sm,
    int w, int bx, int b, int h)
{
    const int tid  = threadIdx.x;
    const int lane = tid & 63;
    const int wave = tid >> 6;
    const int q0 = (bx * 4 + wave) * 16;
    const size_t bs = (size_t)b * 1024;

    const int fr  = lane & 15;
    const int grp = lane >> 4;
    const int fk8 = grp * 8;

    f16* vsw = sm + wave * 2560;

    f16x8 aq[2];
    {
        const f16* qp = qkv + (bs + q0 + fr) * 1536 + h * 64 + fk8;
        aq[0] = *(const f16x8*)qp;
        aq[1] = *(const f16x8*)(qp + 32);
#pragma unroll
        for (int e = 0; e < 8; ++e) {
            aq[0][e] *= (f16)0.18033688;
            aq[1][e] *= (f16)0.18033688;
        }
    }

    f16x8 bk[2][2];
#pragma unroll
    for (int g = 0; g < 2; ++g) {
        int krow = q0 - 16 + g * 16 + fr;
        int kcl  = krow < 0 ? 0 : krow;
        const f16* kp = qkv + (bs + kcl) * 1536 + 512 + h * 64 + fk8;
        bk[g][0] = *(const f16x8*)kp;
        bk[g][1] = *(const f16x8*)(kp + 32);
    }

    {
        const int vk = lane & 31;
        const int vd = (lane >> 5) * 32;
        int vrow = q0 - 16 + vk;
        int vcl  = vrow < 0 ? 0 : vrow;
        const f16* vp = qkv + (bs + vcl) * 1536 + 1024 + h * 64 + vd;
#pragma unroll
        for (int t = 0; t < 4; ++t) {
            f16x8 vv = *(const f16x8*)(vp + t * 8);
#pragma unroll
            for (int e = 0; e < 8; ++e)
                vsw[(vd + t * 8 + e) * 40 + vk] = vv[e];
        }
    }

    const f32x4 fz = (f32x4){0.f, 0.f, 0.f, 0.f};
    f32x4 s[2];
#pragma unroll
    for (int g = 0; g < 2; ++g) {
        f32x4 z = __builtin_amdgcn_mfma_f32_16x16x32_f16(
            bk[g][0], aq[0], fz, 0, 0, 0);
        s[g] = __builtin_amdgcn_mfma_f32_16x16x32_f16(
            bk[g][1], aq[1], z, 0, 0, 0);
    }

    unsigned int dw[2][2];
#pragma unroll
    for (int g = 0; g < 2; ++g) {
        float p[4];
#pragma unroll
        for (int r = 0; r < 4; ++r) {
            const int kin  = g * 16 + grp * 4 + r;
            const int kpos = q0 - 16 + kin;
            const int diff = fr - kin + 16;
            const bool ok = (diff >= 0) && (diff < w) && (kpos >= 0);
            p[r] = ok ? exp2f(fminf(s[g][r], 15.9f)) : 0.f;
        }
        f16x2 h0 = { (f16)p[0], (f16)p[1] };
        f16x2 h1 = { (f16)p[2], (f16)p[3] };
        dw[g][0] = __builtin_bit_cast(unsigned int, h0);
        dw[g][1] = __builtin_bit_cast(unsigned int, h1);
    }

    unsigned int pdw[4];
#pragma unroll
    for (int T = 0; T < 2; ++T) {
        unsigned int X = dw[0][T];
        unsigned int Y = dw[1][T];
        asm("v_permlane32_swap_b32 %0, %1" : "+v"(X), "+v"(Y));
        asm("v_permlane16_swap_b32 %0, %1" : "+v"(X), "+v"(Y));
        pdw[T]     = X;
        pdw[2 + T] = Y;
    }
    union { unsigned int u[4]; f16x8 hv; } cu;
    cu.u[0] = pdw[0]; cu.u[1] = pdw[1]; cu.u[2] = pdw[2]; cu.u[3] = pdw[3];
    const f16x8 paf = cu.hv;

    f16x8 onesf;
#pragma unroll
    for (int e = 0; e < 8; ++e) onesf[e] = (f16)1.0f;
    f32x4 lacc = __builtin_amdgcn_mfma_f32_16x16x32_f16(paf, onesf, fz, 0, 0, 0);

    __builtin_amdgcn_wave_barrier();

    f32x4 acc[4];
#pragma unroll
    for (int j = 0; j < 4; ++j) {
        f16x8 bv = *(const f16x8*)&vsw[(j * 16 + fr) * 40 + fk8];
        acc[j] = __builtin_amdgcn_mfma_f32_16x16x32_f16(paf, bv, fz, 0, 0, 0);
    }

    float inv[4];
#pragma unroll
    for (int r = 0; r < 4; ++r) inv[r] = 1.0f / lacc[r];
#pragma unroll
    for (int j = 0; j < 4; ++j)
#pragma unroll
        for (int r = 0; r < 4; ++r) {
            const int q = q0 + grp * 4 + r;
            out[(bs + q) * 1536 + h * 64 + j * 16 + fr] =
                (f16)(acc[j][r] * inv[r]);
        }
}

// ---------------------------------------------------------------------------
// Full attention body (unchanged)
// ---------------------------------------------------------------------------
__device__ __forceinline__ void full_attn_body(
    const f16* __restrict__ qkv, f16* __restrict__ out, f16* sm,
    int bx, int b, int h)
{
    const int tid  = threadIdx.x;
    const int lane = tid & 63;
    const int wave = tid >> 6;
    const int q0 = bx * 128;
    const size_t bs = (size_t)b * 1024;

    const int fr  = lane & 15;
    const int grp = lane >> 4;
    const int fk8 = grp * 8;

    f16x8 aq[2][2];
#pragma unroll
    for (int qt = 0; qt < 2; ++qt) {
        const f16* qp = qkv + (bs + q0 + wave * 32 + qt * 16 + fr) * 1536
                        + h * 64 + fk8;
        aq[qt][0] = *(const f16x8*)qp;
        aq[qt][1] = *(const f16x8*)(qp + 32);
#pragma unroll
        for (int e = 0; e < 8; ++e) {
            aq[qt][0][e] *= (f16)0.18033688;
            aq[qt][1][e] *= (f16)0.18033688;
        }
    }

    f16x8 onesf;
#pragma unroll
    for (int e = 0; e < 8; ++e) onesf[e] = (f16)1.0f;

    const f32x4 fz = (f32x4){0.f, 0.f, 0.f, 0.f};
    f32x4 lacc[2] = {fz, fz};
    f32x4 acc[2][4];
#pragma unroll
    for (int qt = 0; qt < 2; ++qt)
#pragma unroll
        for (int j = 0; j < 4; ++j)
            acc[qt][j] = fz;

    const int kr = tid >> 2, kc = (tid & 3) * 16;
    const int kp = (tid & 31) * 2, cb = (tid >> 5) * 8;

    const f16* kgp = qkv + (bs + kr) * 1536 + 512 + h * 64 + kc;
    const f16* vgp = qkv + (bs + kp) * 1536 + 1024 + h * 64 + cb;

    f16x8 ka, kb, va, vb;
    ka = *(const f16x8*)kgp; kb = *(const f16x8*)(kgp + 8);
    va = *(const f16x8*)vgp; vb = *(const f16x8*)(vgp + 1536);

    {
        f16* ks = sm + kr * 72 + kc;
        *(f16x8*)ks = ka; *(f16x8*)(ks + 8) = kb;
        f16* vs = sm + 9216 + kp;
#pragma unroll
        for (int e = 0; e < 8; ++e) {
            f16x2 pr = { va[e], vb[e] };
            *(f16x2*)&vs[(cb + e) * 72] = pr;
        }
    }
    kgp += 64 * 1536; vgp += 64 * 1536;
    ka = *(const f16x8*)kgp; kb = *(const f16x8*)(kgp + 8);
    va = *(const f16x8*)vgp; vb = *(const f16x8*)(vgp + 1536);

    for (int t = 0; t < 16; ++t) {
        __syncthreads();
        const int p = t & 1;
        const f16* Ksp = sm + p * 4608;
        const f16* Vsp = sm + 9216 + p * 4608;

        if (t + 1 < 16) {
            f16* ks = sm + (p ^ 1) * 4608 + kr * 72 + kc;
            *(f16x8*)ks = ka; *(f16x8*)(ks + 8) = kb;
            f16* vs = sm + 9216 + (p ^ 1) * 4608 + kp;
#pragma unroll
            for (int e = 0; e < 8; ++e) {
                f16x2 pr = { va[e], vb[e] };
                *(f16x2*)&vs[(cb + e) * 72] = pr;
            }
            if (t + 2 < 16) {
                kgp += 64 * 1536; vgp += 64 * 1536;
                ka = *(const f16x8*)kgp; kb = *(const f16x8*)(kgp + 8);
                va = *(const f16x8*)vgp; vb = *(const f16x8*)(vgp + 1536);
            }
        }

        // hoisted K fragments (qt-invariant): K[j*16+fr][c*32 + grp*8 + e]
        f16x8 kf[4][2];
#pragma unroll
        for (int j = 0; j < 4; ++j)
#pragma unroll
            for (int c = 0; c < 2; ++c)
                kf[j][c] = *(const f16x8*)&Ksp[(j * 16 + fr) * 72 + c * 32 + fk8];

        f16x8 paf[2][2];
#pragma unroll
        for (int qt = 0; qt < 2; ++qt) {
            f32x4 s2[4];
#pragma unroll
            for (int j = 0; j < 4; ++j) {
                f32x4 z = __builtin_amdgcn_mfma_f32_16x16x32_f16(
                        kf[j][0], aq[qt][0], fz, 0, 0, 0);
                s2[j] = __builtin_amdgcn_mfma_f32_16x16x32_f16(
                        kf[j][1], aq[qt][1], z, 0, 0, 0);
            }

            unsigned int dw[4][2];
#pragma unroll
            for (int j = 0; j < 4; ++j) {
                float p0 = exp2f(fminf(s2[j][0], 15.9f));
                float p1 = exp2f(fminf(s2[j][1], 15.9f));
                float p2 = exp2f(fminf(s2[j][2], 15.9f));
                float p3 = exp2f(fminf(s2[j][3], 15.9f));
                f16x2 h0 = { (f16)p0, (f16)p1 };
                f16x2 h1 = { (f16)p2, (f16)p3 };
                dw[j][0] = __builtin_bit_cast(unsigned int, h0);
                dw[j][1] = __builtin_bit_cast(unsigned int, h1);
            }

            unsigned int pdw[2][4];
#pragma unroll
            for (int c = 0; c < 2; ++c)
#pragma unroll
                for (int T = 0; T < 2; ++T) {
                    unsigned int X = dw[2 * c][T];
                    unsigned int Y = dw[2 * c + 1][T];
                    asm("v_permlane32_swap_b32 %0, %1" : "+v"(X), "+v"(Y));
                    asm("v_permlane16_swap_b32 %0, %1" : "+v"(X), "+v"(Y));
                    pdw[c][T]     = X;
                    pdw[c][2 + T] = Y;
                }
            union { unsigned int u[4]; f16x8 hv; } cu;
#pragma unroll
            for (int c = 0; c < 2; ++c) {
                cu.u[0] = pdw[c][0]; cu.u[1] = pdw[c][1];
                cu.u[2] = pdw[c][2]; cu.u[3] = pdw[c][3];
                paf[qt][c] = cu.hv;
            }

            lacc[qt] = __builtin_amdgcn_mfma_f32_16x16x32_f16(
                paf[qt][0], onesf, lacc[qt], 0, 0, 0);
            lacc[qt] = __builtin_amdgcn_mfma_f32_16x16x32_f16(
                paf[qt][1], onesf, lacc[qt], 0, 0, 0);
        }

        f16x8 vf[4][2];
#pragma unroll
        for (int j = 0; j < 4; ++j)
#pragma unroll
            for (int c = 0; c < 2; ++c)
                vf[j][c] = *(const f16x8*)&Vsp[(j * 16 + fr) * 72 + c * 32 + fk8];

#pragma unroll
        for (int qt = 0; qt < 2; ++qt)
#pragma unroll
            for (int j = 0; j < 4; ++j)
#pragma unroll
                for (int c = 0; c < 2; ++c)
                    acc[qt][j] = __builtin_amdgcn_mfma_f32_16x16x32_f16(
                        paf[qt][c], vf[j][c], acc[qt][j], 0, 0, 0);
    }

#pragma unroll
    for (int qt = 0; qt < 2; ++qt) {
        float inv[4];
#pragma unroll
        for (int r = 0; r < 4; ++r) inv[r] = 1.0f / lacc[qt][r];
#pragma unroll
        for (int j = 0; j < 4; ++j)
#pragma unroll
            for (int r = 0; r < 4; ++r) {
                const int q = q0 + wave * 32 + qt * 16 + grp * 4 + r;
                out[(bs + q) * 1536 + h * 64 + j * 16 + fr] =
                    (f16)(acc[qt][j][r] * inv[r]);
            }
    }
}

// ---------------------------------------------------------------------------
// standalone kernels (fallback path)
// ---------------------------------------------------------------------------
__global__ __launch_bounds__(256) void win_attn_mfma(
    const f16* __restrict__ qkv, f16* __restrict__ out, int w)
{
    __shared__ __align__(16) f16 sm[4 * 2560];
    win_attn_body(qkv, out, sm, w, blockIdx.x, blockIdx.y, blockIdx.z);
}

__global__ __launch_bounds__(256, 4) void full_attn_mfma(
    const f16* __restrict__ qkv, f16* __restrict__ out)
{
    __shared__ __align__(16) f16 sm[18432];
    full_attn_body(qkv, out, sm, blockIdx.x, blockIdx.y, blockIdx.z);
}

// ---------------------------------------------------------------------------
// fused attention (unchanged)
// ---------------------------------------------------------------------------
__global__ __launch_bounds__(256, 4) void attn_all(
    const f16* __restrict__ q0b, const f16* __restrict__ q1b,
    const f16* __restrict__ q2b, f16* __restrict__ cat)
{
    __shared__ __align__(16) f16 sm[18432];
    const int bid = blockIdx.x;
    if (bid < 1024) {
        full_attn_body(q2b, cat + 1024, sm, bid & 7, (bid >> 3) & 15, bid >> 7);
    } else if (bid < 3072) {
        const int i = bid - 1024;
        win_attn_body(q0b, cat, sm, 5, i & 15, (i >> 4) & 15, i >> 8);
    } else {
        const int i = bid - 3072;
        win_attn_body(q1b, cat + 512, sm, 10, i & 15, (i >> 4) & 15, i >> 8);
    }
}

// ---------------------------------------------------------------------------
// launch
// ---------------------------------------------------------------------------
extern "C" void kernel_launch(void* const* d_in, const int* in_sizes, int n_in,
                              void* d_out, int out_size, void* d_ws, size_t ws_size,
                              hipStream_t stream)
{
    const float* x    = (const float*)d_in[0];   // [16,1024,512]
    const float* Wqkv = (const float*)d_in[1];   // [3,1536,512]
    const float* bqkv = (const float*)d_in[2];   // [3,1536]
    const float* Wo   = (const float*)d_in[3];   // [3,512,512]
    const float* bo   = (const float*)d_in[4];   // [3,512] (flat 1536)
    const float* Wf   = (const float*)d_in[5];   // [512,1536]
    const float* bfin = (const float*)d_in[6];   // [512]
    float* out = (float*)d_out;                  // [16,1024,512] fp32

    f16* xh    = (f16*)d_out;                          // 16.8 MB scratch
    f16* wqkvh = (f16*)((char*)d_out + 16777216);      // 4.7 MB scratch
    char* ws = (char*)d_ws;

    const size_t QKV_EL = 25165824;          // 16384*1536 f16 elements
    const size_t QKV_B  = 50331648;          // bytes

    const bool fused = ws_size >= (size_t)206047232;

    if (fused) {
        f16*   qkv0     = (f16*)ws;
        f16*   attn_cat = (f16*)(ws + 3 * QKV_B);
        f16*   wfh      = (f16*)(ws + 3 * QKV_B + QKV_B);
        f16*   WoT      = (f16*)((char*)wfh + 1572864);
        f16*   Wfo      = (f16*)((char*)WoT + 1572864);
        float* bp       = (float*)((char*)Wfo + 1572864);

        prep_all<<<dim3(6528), 256, 0, stream>>>(
            x, Wqkv, Wf, Wo, bo, bfin, xh, wqkvh, wfh, WoT, bp);

        gemm_mfma_nt<f16><<<dim3(4, 4, 3), 256, 0, stream>>>(
            wfh, 1536, 512, WoT, 512, 262144, nullptr, Wfo, 1536, 512, 512);

        gemm_mfma_8ph<3, 8, f16><<<dim3(8, 128, 3), 512, 0, stream>>>(
            xh, 512, wqkvh, 512, 786432, bqkv, 1536,
            qkv0, 1536, (long)QKV_EL);

        attn_all<<<dim3(5120), 256, 0, stream>>>(
            qkv0, qkv0 + QKV_EL, qkv0 + 2 * QKV_EL, attn_cat);

        gemm_mfma_8ph<2, 24, float><<<dim3(4, 128, 1), 512, 0, stream>>>(
            attn_cat, 1536, Wfo, 1536, 0, bp, 0, out, 512, 0);
    } else {
        f16*   qkvbuf   = (f16*)ws;
        f16*   attn_cat = (f16*)(ws + QKV_B);
        f16*   wfh      = (f16*)(ws + 2 * QKV_B);
        f16*   WoT      = (f16*)(ws + 2 * QKV_B + 1572864);
        f16*   Wfo      = (f16*)(ws + 2 * QKV_B + 2 * 1572864);
        float* bp       = (float*)(ws + 2 * QKV_B + 3 * 1572864);

        prep_all<<<dim3(6528), 256, 0, stream>>>(
            x, Wqkv, Wf, Wo, bo, bfin, xh, wqkvh, wfh, WoT, bp);

        gemm_mfma_nt<f16><<<dim3(4, 4, 3), 256, 0, stream>>>(
            wfh, 1536, 512, WoT, 512, 262144, nullptr, Wfo, 1536, 512, 512);

        for (int i = 0; i < 3; ++i) {
            gemm_mfma_8ph<3, 8, f16><<<dim3(8, 128, 1), 512, 0, stream>>>(
                xh, 512, wqkvh + (size_t)i * 786432, 512, 0,
                bqkv + i * 1536, 0, qkvbuf, 1536, 0);

            if (i == 0)
                win_attn_mfma<<<dim3(16, 16, 8), 256, 0, stream>>>(
                    qkvbuf, attn_cat + 0 * 512, 5);
            else if (i == 1)
                win_attn_mfma<<<dim3(16, 16, 8), 256, 0, stream>>>(
                    qkvbuf, attn_cat + 1 * 512, 10);
            else
                full_attn_mfma<<<dim3(8, 16, 8), 256, 0, stream>>>(
                    qkvbuf, attn_cat + 2 * 512);
        }

        gemm_mfma_8ph<2, 24, float><<<dim3(4, 128, 1), 512, 0, stream>>>(
            attn_cat, 1536, Wfo, 1536, 0, bp, 0, out, 512, 0);
    }
}